// Round 3
// baseline (58.888 us; speedup 1.0000x reference)
//
#include <hip/hip_runtime.h>
#include <hip/hip_bf16.h>
#include <math.h>

// ---------------------------------------------------------------------------
// Bispectrum of 2D FFT, REAL PART ONLY (harness grades float32 view):
//   out[b,p,q] = Re( X[b,p] * X[b,q] * conj(X[b, p (+) q]) )
// with X = fft2(x), x: (2, 64, 64) f32, p,q flat over 64x64, (+) = per-axis
// modular index addition. Output (2, 4096, 4096) float32.
// ---------------------------------------------------------------------------

#define M 64
#define MN 4096  // 64*64
#define MAX_B 16

// Static device-global scratch for X = fft2(x) (no ws_size assumptions).
__device__ float2 g_X[MAX_B * MN];

// One block per batch: two-pass naive DFT (rows then cols) in LDS.
__global__ __launch_bounds__(1024) void fft2_64x64_kernel(
    const float* __restrict__ x) {
  __shared__ float sx[MN];
  __shared__ float Wre[M];
  __shared__ float Wim[M];
  __shared__ float Yre[MN];
  __shared__ float Yim[MN];

  const int b = blockIdx.x;
  const int t = threadIdx.x;

#pragma unroll
  for (int k = 0; k < 4; ++k) {
    sx[t + k * 1024] = x[b * MN + t + k * 1024];
  }
  if (t < M) {
    float s, c;
    sincosf(2.0f * 3.14159265358979323846f * (float)t / 64.0f, &s, &c);
    Wre[t] = c;
    Wim[t] = -s;
  }
  __syncthreads();

  // Row pass: Y[r,u] = sum_j x[r,j] * W[(j*u) & 63]   (x real)
#pragma unroll
  for (int k = 0; k < 4; ++k) {
    const int e = t + k * 1024;
    const int r = e >> 6;
    const int u = e & 63;
    float are = 0.0f, aim = 0.0f;
#pragma unroll 8
    for (int j = 0; j < M; ++j) {
      const float xv = sx[(r << 6) + j];
      const int w = (j * u) & 63;
      are = fmaf(xv, Wre[w], are);
      aim = fmaf(xv, Wim[w], aim);
    }
    Yre[e] = are;
    Yim[e] = aim;
  }
  __syncthreads();

  // Col pass: X[v,c] = sum_r Y[r,c] * W[(r*v) & 63]
#pragma unroll
  for (int k = 0; k < 4; ++k) {
    const int e = t + k * 1024;
    const int v = e >> 6;
    const int c = e & 63;
    float are = 0.0f, aim = 0.0f;
#pragma unroll 8
    for (int r = 0; r < M; ++r) {
      const float yre = Yre[(r << 6) + c];
      const float yim = Yim[(r << 6) + c];
      const int w = (r * v) & 63;
      const float wr = Wre[w];
      const float wi = Wim[w];
      are = fmaf(yre, wr, fmaf(-yim, wi, are));
      aim = fmaf(yre, wi, fmaf(yim, wr, aim));
    }
    g_X[(b << 12) + e] = make_float2(are, aim);
  }
}

// One block per (b, p) output row; Xb staged in LDS. 256 threads x 4 chunks
// x 4 floats = 4096 float outputs per row, coalesced float4 stores.
__global__ __launch_bounds__(256) void bispectrum_kernel(
    float* __restrict__ out) {
  __shared__ float2 sX[MN];  // 32 KB

  const int blk = blockIdx.x;  // b*4096 + p
  const int b = blk >> 12;
  const int p = blk & (MN - 1);
  const float2* __restrict__ Xb = g_X + ((size_t)b << 12);
  const int t = threadIdx.x;

#pragma unroll
  for (int k = 0; k < 16; ++k) {
    sX[t + k * 256] = Xb[t + k * 256];
  }
  __syncthreads();

  const float2 Xp = sX[p];
  const int i1 = p >> 6;
  const int j1 = p & 63;

  float* __restrict__ row = out + ((size_t)blk << 12);

#pragma unroll
  for (int c = 0; c < 4; ++c) {
    const int q = (c << 10) + (t << 2);  // multiple of 4; j2 in [0,60]
    const float4 xq01 = *reinterpret_cast<const float4*>(sX + q);
    const float4 xq23 = *reinterpret_cast<const float4*>(sX + q + 2);
    const int i2 = q >> 6;
    const int j2 = q & 63;
    const int ci = ((i1 + i2) & 63) << 6;
    const int js = j1 + j2;

    const float2 t0 = sX[ci + (js & 63)];
    const float2 t1 = sX[ci + ((js + 1) & 63)];
    const float2 t2 = sX[ci + ((js + 2) & 63)];
    const float2 t3 = sX[ci + ((js + 3) & 63)];

    float4 res;
    {
      const float ure = Xp.x * xq01.x - Xp.y * xq01.y;
      const float uim = Xp.x * xq01.y + Xp.y * xq01.x;
      res.x = ure * t0.x + uim * t0.y;
    }
    {
      const float ure = Xp.x * xq01.z - Xp.y * xq01.w;
      const float uim = Xp.x * xq01.w + Xp.y * xq01.z;
      res.y = ure * t1.x + uim * t1.y;
    }
    {
      const float ure = Xp.x * xq23.x - Xp.y * xq23.y;
      const float uim = Xp.x * xq23.y + Xp.y * xq23.x;
      res.z = ure * t2.x + uim * t2.y;
    }
    {
      const float ure = Xp.x * xq23.z - Xp.y * xq23.w;
      const float uim = Xp.x * xq23.w + Xp.y * xq23.z;
      res.w = ure * t3.x + uim * t3.y;
    }
    *reinterpret_cast<float4*>(row + q) = res;
  }
}

extern "C" void kernel_launch(void* const* d_in, const int* in_sizes, int n_in,
                              void* d_out, int out_size, void* d_ws, size_t ws_size,
                              hipStream_t stream) {
  const float* x = (const float*)d_in[0];
  float* out = (float*)d_out;
  int B = in_sizes[0] >> 12;  // elements / 4096 = batch count (2)
  if (B < 1) B = 1;
  if (B > MAX_B) B = MAX_B;

  fft2_64x64_kernel<<<B, 1024, 0, stream>>>(x);
  bispectrum_kernel<<<B * MN, 256, 0, stream>>>(out);
}

// Round 4
// 35.496 us; speedup vs baseline: 1.6590x; 1.6590x over previous
//
#include <hip/hip_runtime.h>
#include <hip/hip_bf16.h>
#include <math.h>

// ---------------------------------------------------------------------------
// Bispectrum of 2D FFT, REAL PART ONLY (harness grades float32 view):
//   out[b,p,q] = Re( X[b,p] * X[b,q] * conj(X[b, p (+) q]) )
// with X = fft2(x), x: (2, 64, 64) f32, p,q flat over 64x64, (+) = per-axis
// modular index addition. Output (2, 4096, 4096) float32.
//
// Structure: 3 kernels.
//  1) fft_rows:  128 blocks x 64 thr  -> Y[b,r,u]  (row DFTs)
//  2) fft_cols:  128 blocks x 64 thr  -> X[b,v,c]  (col DFTs)
//  3) bispectrum: B*1024 blocks x 256 thr, 4 output rows per block,
//     no LDS (X is L1-resident), sliding-window conj-row gathers.
// ---------------------------------------------------------------------------

#define M 64
#define MN 4096  // 64*64
#define MAX_B 16
#define G 4      // output rows per bispectrum block

__device__ __align__(16) float2 g_X[MAX_B * MN];
__device__ __align__(16) float2 g_Y[MAX_B * MN];

#define TWO_PI 6.28318530717958647692f

// Row DFT: one block per (b, r). Thread u: Y[r,u] = sum_j x[r,j] W[(j*u)&63].
__global__ __launch_bounds__(64) void fft_rows_kernel(
    const float* __restrict__ x) {
  __shared__ float2 W[M];
  const int blk = blockIdx.x;  // b*64 + r
  const int u = threadIdx.x;
  {
    float s, c;
    sincosf(TWO_PI * (float)u / 64.0f, &s, &c);
    W[u] = make_float2(c, -s);  // exp(-2*pi*i*u/64)
  }
  __syncthreads();

  const float* __restrict__ xr = x + (blk << 6);
  float are = 0.0f, aim = 0.0f;
#pragma unroll
  for (int j = 0; j < M; ++j) {
    const float xv = xr[j];  // wave-uniform address (L1 broadcast)
    const float2 w = W[(j * u) & 63];
    are = fmaf(xv, w.x, are);
    aim = fmaf(xv, w.y, aim);
  }
  g_Y[(blk << 6) + u] = make_float2(are, aim);
}

// Col DFT: one block per (b, c). Thread v: X[v,c] = sum_r Y[r,c] W[(r*v)&63].
__global__ __launch_bounds__(64) void fft_cols_kernel() {
  __shared__ float2 W[M];
  __shared__ float2 sY[M];
  const int blk = blockIdx.x;  // b*64 + c
  const int b = blk >> 6;
  const int c = blk & 63;
  const int v = threadIdx.x;
  {
    float s, cc;
    sincosf(TWO_PI * (float)v / 64.0f, &s, &cc);
    W[v] = make_float2(cc, -s);
  }
  sY[v] = g_Y[(b << 12) + (v << 6) + c];  // stage the column
  __syncthreads();

  float are = 0.0f, aim = 0.0f;
#pragma unroll
  for (int r = 0; r < M; ++r) {
    const float2 y = sY[r];  // wave-uniform LDS read (broadcast, free)
    const float2 w = W[(r * v) & 63];
    are = fmaf(y.x, w.x, fmaf(-y.y, w.y, are));
    aim = fmaf(y.x, w.y, fmaf(y.y, w.x, aim));
  }
  g_X[(b << 12) + (v << 6) + c] = make_float2(are, aim);
}

// Bispectrum: one block per G=4 consecutive output rows (same batch, same
// i1 row since p0 % 4 == 0 guarantees j1+g <= 63). 256 threads, each thread
// writes one float4 per (chunk, g): 4 chunks x 4 rows = 16 float4 stores.
// X read directly from global (L1-resident, 32 KB per batch). The conj-row
// values for the 4 rows form a sliding window: 7 loads serve 4 rows.
__global__ __launch_bounds__(256) void bispectrum_kernel(
    float* __restrict__ out) {
  const int blk = blockIdx.x;   // (b*4096 + p0) / G
  const int base = blk << 2;    // b*4096 + p0
  const int b = base >> 12;
  const int p0 = base & (MN - 1);
  const float2* __restrict__ Xb = g_X + (b << 12);
  const int t = threadIdx.x;

  const int i1 = p0 >> 6;
  const int j1 = p0 & 63;  // j1 + G - 1 <= 63 (p0 multiple of 4)

  float2 Xp[G];
#pragma unroll
  for (int g = 0; g < G; ++g) Xp[g] = Xb[p0 + g];

  float* __restrict__ out0 = out + ((size_t)base << 12);

#pragma unroll
  for (int c = 0; c < 4; ++c) {
    const int q = (c << 10) + (t << 2);  // this lane's first complex index
    const float4 xa = *reinterpret_cast<const float4*>(Xb + q);      // q,q+1
    const float4 xc = *reinterpret_cast<const float4*>(Xb + q + 2);  // q+2,q+3
    const int i2 = q >> 6;
    const int j2 = q & 63;
    const int ci = ((i1 + i2) & 63) << 6;
    const int js0 = j1 + j2;

    // Sliding window of conj-row values: rows g use tv[g..g+3].
    float2 tv[G + 3];
#pragma unroll
    for (int k = 0; k < G + 3; ++k) {
      tv[k] = Xb[ci + ((js0 + k) & 63)];
    }

#pragma unroll
    for (int g = 0; g < G; ++g) {
      const float2 P = Xp[g];
      float4 res;
      {
        const float ur = P.x * xa.x - P.y * xa.y;
        const float ui = P.x * xa.y + P.y * xa.x;
        res.x = ur * tv[g].x + ui * tv[g].y;
      }
      {
        const float ur = P.x * xa.z - P.y * xa.w;
        const float ui = P.x * xa.w + P.y * xa.z;
        res.y = ur * tv[g + 1].x + ui * tv[g + 1].y;
      }
      {
        const float ur = P.x * xc.x - P.y * xc.y;
        const float ui = P.x * xc.y + P.y * xc.x;
        res.z = ur * tv[g + 2].x + ui * tv[g + 2].y;
      }
      {
        const float ur = P.x * xc.z - P.y * xc.w;
        const float ui = P.x * xc.w + P.y * xc.z;
        res.w = ur * tv[g + 3].x + ui * tv[g + 3].y;
      }
      *reinterpret_cast<float4*>(out0 + ((size_t)g << 12) + q) = res;
    }
  }
}

extern "C" void kernel_launch(void* const* d_in, const int* in_sizes, int n_in,
                              void* d_out, int out_size, void* d_ws, size_t ws_size,
                              hipStream_t stream) {
  const float* x = (const float*)d_in[0];
  float* out = (float*)d_out;
  int B = in_sizes[0] >> 12;  // elements / 4096 = batch count (2)
  if (B < 1) B = 1;
  if (B > MAX_B) B = MAX_B;

  fft_rows_kernel<<<B * M, M, 0, stream>>>(x);
  fft_cols_kernel<<<B * M, M, 0, stream>>>();
  bispectrum_kernel<<<B * (MN / G), 256, 0, stream>>>(out);
}

// Round 5
// 32.996 us; speedup vs baseline: 1.7847x; 1.0757x over previous
//
#include <hip/hip_runtime.h>
#include <hip/hip_bf16.h>
#include <math.h>

// ---------------------------------------------------------------------------
// Bispectrum of 2D FFT, REAL PART ONLY (harness grades float32 view):
//   out[b,p,q] = Re( X[b,p] * X[b,q] * conj(X[b, p (+) q]) )
// with X = fft2(x), x: (2, 64, 64) f32, p,q flat over 64x64, (+) = per-axis
// modular index addition. Output (2, 4096, 4096) float32.
//
// Structure: 2 kernels.
//  1) fft2_fused: B*8 blocks x 512 thr. Each block owns 8 output columns:
//     row-DFT restricted to those columns (from LDS-transposed x), then
//     col-DFT. One launch, no global Y round-trip.
//  2) bispectrum: B*1024 blocks x 256 thr, 4 output rows per block,
//     no LDS (X is L1-resident), sliding-window conj-row gathers.
// ---------------------------------------------------------------------------

#define M 64
#define MN 4096  // 64*64
#define MAX_B 16
#define G 4      // output rows per bispectrum block

__device__ __align__(16) float2 g_X[MAX_B * MN];

#define TWO_PI 6.28318530717958647692f

// Fused 2D DFT. Block = (b, column-group of 8). Threads: 512.
//  Row phase: thread (r, cl) computes Y[r, c0+cl] = sum_j x[r,j] W[(j*(c0+cl))&63]
//  Col phase: thread (v, cl) computes X[v, c0+cl] = sum_r Y[r, cl] W[(r*v)&63]
__global__ __launch_bounds__(512) void fft2_fused_kernel(
    const float* __restrict__ x) {
  __shared__ float sxT[M * (M + 1)];  // transposed + padded: sxT[j*65 + r]
  __shared__ float2 W[M];
  __shared__ float2 sY[M * 8];        // sY[r*8 + cl]

  const int blk = blockIdx.x;  // b*8 + cg
  const int b = blk >> 3;
  const int c0 = (blk & 7) << 3;
  const int tt = threadIdx.x;

  if (tt < M) {
    float s, c;
    sincosf(TWO_PI * (float)tt / 64.0f, &s, &c);
    W[tt] = make_float2(c, -s);  // exp(-2*pi*i*tt/64)
  }
  // Stage x transposed: banks (j + r) & 31 -> write 2-way (free), read clean.
#pragma unroll
  for (int k = 0; k < 8; ++k) {
    const int idx = tt + (k << 9);
    const int r = idx >> 6;
    const int j = idx & 63;
    sxT[j * 65 + r] = x[(b << 12) + idx];
  }
  __syncthreads();

  // Row phase.
  {
    const int r = tt >> 3;
    const int cl = tt & 7;
    const int u = c0 + cl;
    float are = 0.0f, aim = 0.0f;
#pragma unroll
    for (int j = 0; j < M; ++j) {
      const float xv = sxT[j * 65 + r];
      const float2 w = W[(j * u) & 63];
      are = fmaf(xv, w.x, are);
      aim = fmaf(xv, w.y, aim);
    }
    sY[r * 8 + cl] = make_float2(are, aim);
  }
  __syncthreads();

  // Col phase.
  {
    const int v = tt >> 3;
    const int cl = tt & 7;
    float are = 0.0f, aim = 0.0f;
#pragma unroll
    for (int r = 0; r < M; ++r) {
      const float2 y = sY[r * 8 + cl];
      const float2 w = W[(r * v) & 63];
      are = fmaf(y.x, w.x, fmaf(-y.y, w.y, are));
      aim = fmaf(y.x, w.y, fmaf(y.y, w.x, aim));
    }
    g_X[(b << 12) + (v << 6) + c0 + cl] = make_float2(are, aim);
  }
}

// Bispectrum: one block per G=4 consecutive output rows (same batch, same
// i1 row since p0 % 4 == 0 guarantees j1+g <= 63). 256 threads, each thread
// writes one float4 per (chunk, g): 4 chunks x 4 rows = 16 float4 stores.
// X read directly from global (L1-resident, 32 KB per batch). The conj-row
// values for the 4 rows form a sliding window: 7 loads serve 4 rows.
__global__ __launch_bounds__(256) void bispectrum_kernel(
    float* __restrict__ out) {
  const int blk = blockIdx.x;   // (b*4096 + p0) / G
  const int base = blk << 2;    // b*4096 + p0
  const int b = base >> 12;
  const int p0 = base & (MN - 1);
  const float2* __restrict__ Xb = g_X + (b << 12);
  const int t = threadIdx.x;

  const int i1 = p0 >> 6;
  const int j1 = p0 & 63;  // j1 + G - 1 <= 63 (p0 multiple of 4)

  // Xp[0..3] as two aligned float4 loads.
  float2 Xp[G];
  {
    const float4 a = *reinterpret_cast<const float4*>(Xb + p0);
    const float4 c = *reinterpret_cast<const float4*>(Xb + p0 + 2);
    Xp[0] = make_float2(a.x, a.y);
    Xp[1] = make_float2(a.z, a.w);
    Xp[2] = make_float2(c.x, c.y);
    Xp[3] = make_float2(c.z, c.w);
  }

  float* __restrict__ out0 = out + ((size_t)base << 12);

#pragma unroll
  for (int c = 0; c < 4; ++c) {
    const int q = (c << 10) + (t << 2);  // this lane's first complex index
    const float4 xa = *reinterpret_cast<const float4*>(Xb + q);      // q,q+1
    const float4 xc = *reinterpret_cast<const float4*>(Xb + q + 2);  // q+2,q+3
    const int i2 = q >> 6;
    const int j2 = q & 63;
    const int ci = ((i1 + i2) & 63) << 6;
    const int js0 = j1 + j2;

    // Sliding window of conj-row values: rows g use tv[g..g+3].
    float2 tv[G + 3];
#pragma unroll
    for (int k = 0; k < G + 3; ++k) {
      tv[k] = Xb[ci + ((js0 + k) & 63)];
    }

#pragma unroll
    for (int g = 0; g < G; ++g) {
      const float2 P = Xp[g];
      float4 res;
      {
        const float ur = P.x * xa.x - P.y * xa.y;
        const float ui = P.x * xa.y + P.y * xa.x;
        res.x = ur * tv[g].x + ui * tv[g].y;
      }
      {
        const float ur = P.x * xa.z - P.y * xa.w;
        const float ui = P.x * xa.w + P.y * xa.z;
        res.y = ur * tv[g + 1].x + ui * tv[g + 1].y;
      }
      {
        const float ur = P.x * xc.x - P.y * xc.y;
        const float ui = P.x * xc.y + P.y * xc.x;
        res.z = ur * tv[g + 2].x + ui * tv[g + 2].y;
      }
      {
        const float ur = P.x * xc.z - P.y * xc.w;
        const float ui = P.x * xc.w + P.y * xc.z;
        res.w = ur * tv[g + 3].x + ui * tv[g + 3].y;
      }
      *reinterpret_cast<float4*>(out0 + ((size_t)g << 12) + q) = res;
    }
  }
}

extern "C" void kernel_launch(void* const* d_in, const int* in_sizes, int n_in,
                              void* d_out, int out_size, void* d_ws, size_t ws_size,
                              hipStream_t stream) {
  const float* x = (const float*)d_in[0];
  float* out = (float*)d_out;
  int B = in_sizes[0] >> 12;  // elements / 4096 = batch count (2)
  if (B < 1) B = 1;
  if (B > MAX_B) B = MAX_B;

  fft2_fused_kernel<<<B * 8, 512, 0, stream>>>(x);
  bispectrum_kernel<<<B * (MN / G), 256, 0, stream>>>(out);
}